// Round 1
// baseline (783.654 us; speedup 1.0000x reference)
//
#include <hip/hip_runtime.h>
#include <hip/hip_bf16.h>

#define D_ 1024
#define H_ 2048
#define H2_ 4096
#define NE 8
#define M_ 8192

typedef short v8s __attribute__((ext_vector_type(8)));
typedef float v4f __attribute__((ext_vector_type(4)));

__device__ __forceinline__ unsigned short f2b(float f) {
    __hip_bfloat16 h = __float2bfloat16(f);
    unsigned short u;
    __builtin_memcpy(&u, &h, sizeof(u));
    return u;
}

// ---------------- prep: x -> bf16 ----------------
__global__ __launch_bounds__(256) void cvt_x_kernel(const float* __restrict__ x,
                                                    unsigned short* __restrict__ xb) {
    size_t total = (size_t)M_ * D_ / 4;
    for (size_t i = (size_t)blockIdx.x * 256 + threadIdx.x; i < total;
         i += (size_t)gridDim.x * 256) {
        float4 v = ((const float4*)x)[i];
        ushort4 o;
        o.x = f2b(v.x); o.y = f2b(v.y); o.z = f2b(v.z); o.w = f2b(v.w);
        ((ushort4*)xb)[i] = o;
    }
}

// ---------------- prep: transpose (R x C) f32 -> (C x R) bf16, per expert ----
template <int R, int C>
__global__ __launch_bounds__(256) void transpose_kernel(const float* __restrict__ in,
                                                        unsigned short* __restrict__ out) {
    __shared__ float tile[32][33];
    int e = blockIdx.z;
    const float* src = in + (size_t)e * R * C;
    unsigned short* dst = out + (size_t)e * R * C;
    int c0 = blockIdx.x * 32;
    int r0 = blockIdx.y * 32;
    int tx = threadIdx.x & 31, ty = threadIdx.x >> 5;
#pragma unroll
    for (int i = 0; i < 4; ++i)
        tile[ty + i * 8][tx] = src[(size_t)(r0 + ty + i * 8) * C + c0 + tx];
    __syncthreads();
#pragma unroll
    for (int i = 0; i < 4; ++i)
        dst[(size_t)(c0 + ty + i * 8) * R + r0 + tx] = f2b(tile[tx][ty + i * 8]);
}

// ---------------- router: scores, top2, compacted expert lists ----------------
__global__ __launch_bounds__(256) void router_kernel(
    const float* __restrict__ x, const float* __restrict__ Wr,
    const float* __restrict__ br, const float* __restrict__ biases,
    int* __restrict__ cnt, int* __restrict__ perm, float* __restrict__ wgt) {
    int wid = threadIdx.x >> 6;
    int lane = threadIdx.x & 63;
    int m = blockIdx.x * 4 + wid;
    if (m >= M_) return;
    const float4* xr = (const float4*)(x + (size_t)m * D_);
    float4 xv[4];
#pragma unroll
    for (int p = 0; p < 4; ++p) xv[p] = xr[p * 64 + lane];
    float s[NE];
#pragma unroll
    for (int n = 0; n < NE; ++n) {
        const float4* wr = (const float4*)(Wr + (size_t)n * D_);
        float acc = 0.f;
#pragma unroll
        for (int p = 0; p < 4; ++p) {
            float4 w4 = wr[p * 64 + lane];
            acc += xv[p].x * w4.x + xv[p].y * w4.y + xv[p].z * w4.z + xv[p].w * w4.w;
        }
#pragma unroll
        for (int off = 32; off; off >>= 1) acc += __shfl_xor(acc, off, 64);
        s[n] = acc + br[n];
    }
    if (lane == 0) {
        float t[NE];
#pragma unroll
        for (int n = 0; n < NE; ++n) t[n] = s[n] + biases[n];
        int i0 = 0;
#pragma unroll
        for (int n = 1; n < NE; ++n) if (t[n] > t[i0]) i0 = n;
        int i1 = -1;
#pragma unroll
        for (int n = 0; n < NE; ++n) {
            if (n == i0) continue;
            if (i1 < 0 || t[n] > t[i1]) i1 = n;
        }
        // pair softmax == full softmax renormalized over the pair (exact identity)
        float mx = fmaxf(s[i0], s[i1]);
        float e0 = expf(s[i0] - mx), e1 = expf(s[i1] - mx);
        float inv = 1.f / (e0 + e1);
        int p0 = atomicAdd(&cnt[i0], 1);
        perm[i0 * M_ + p0] = m;
        wgt[i0 * M_ + p0] = e0 * inv;
        int p1 = atomicAdd(&cnt[i1], 1);
        perm[i1 * M_ + p1] = m;
        wgt[i1 * M_ + p1] = e1 * inv;
    }
}

__global__ void base_kernel(const int* __restrict__ cnt, int* __restrict__ base) {
    if (threadIdx.x == 0) {
        int b = 0;
        for (int n = 0; n < NE; ++n) { base[n] = b; b += cnt[n]; }
    }
}

// ---------------- GEMM1: act = silu(Xg@W1a + b1a) * (Xg@W1b + b1b) ----------------
// tile 64 rows x 128 cols (= 64 a-cols + 64 b-cols arranged so each wave's
// n-frags 0,1 are a-cols and 2,3 are the paired b-cols: lane-local gating)
__global__ __launch_bounds__(256) void gemm1_kernel(
    const unsigned short* __restrict__ xb, const unsigned short* __restrict__ W1T,
    const float* __restrict__ bl1, const int* __restrict__ cnt,
    const int* __restrict__ base, const int* __restrict__ perm,
    unsigned short* __restrict__ act) {
    int e = blockIdx.z;
    int cn = cnt[e];
    int tm = blockIdx.x;
    if (tm * 64 >= cn) return;
    int ja = blockIdx.y;  // pair block: h-pairs [ja*64, ja*64+64)
    __shared__ __align__(16) unsigned short As[64 * 32];
    __shared__ __align__(16) unsigned short Bs[128 * 32];
    int tid = threadIdx.x, lane = tid & 63, wid = tid >> 6;
    int wm = wid >> 1, wn = wid & 1;
    v4f acc[2][4];
#pragma unroll
    for (int i = 0; i < 2; ++i)
#pragma unroll
        for (int n = 0; n < 4; ++n)
#pragma unroll
            for (int r = 0; r < 4; ++r) acc[i][n][r] = 0.f;

    int ar = tid >> 2, ag = tid & 3;
    int ap = tm * 64 + ar;
    int tok = (ap < cn) ? perm[e * M_ + ap] : -1;
    const unsigned short* w1e = W1T + (size_t)e * H2_ * D_;  // (4096 x 1024) bf16

    int fr = lane & 15, fg = lane >> 4;
    int sg = (fg ^ (fr & 3)) << 3;

    for (int k0 = 0; k0 < D_; k0 += 32) {
        v8s av = {0, 0, 0, 0, 0, 0, 0, 0};
        if (tok >= 0) av = *(const v8s*)(xb + (size_t)tok * D_ + k0 + ag * 8);
        *(v8s*)(As + ar * 32 + ((ag ^ (ar & 3)) << 3)) = av;
#pragma unroll
        for (int rep = 0; rep < 2; ++rep) {
            int item = tid + rep * 256;
            int c = item >> 2, g = item & 3;
            int cc = c & 63, wnc = c >> 6;
            int half = (cc >> 5) & 1;
            int p = wnc * 32 + (cc & 31);
            int grow = half * H_ + ja * 64 + p;
            v8s bv = *(const v8s*)(w1e + (size_t)grow * D_ + k0 + g * 8);
            *(v8s*)(Bs + c * 32 + ((g ^ (c & 3)) << 3)) = bv;
        }
        __syncthreads();
        v8s a[2], b[4];
#pragma unroll
        for (int i = 0; i < 2; ++i)
            a[i] = *(const v8s*)(As + (wm * 32 + i * 16 + fr) * 32 + sg);
#pragma unroll
        for (int n = 0; n < 4; ++n)
            b[n] = *(const v8s*)(Bs + (wn * 64 + n * 16 + fr) * 32 + sg);
#pragma unroll
        for (int i = 0; i < 2; ++i)
#pragma unroll
            for (int n = 0; n < 4; ++n)
                acc[i][n] = __builtin_amdgcn_mfma_f32_16x16x32_bf16(a[i], b[n], acc[i][n], 0, 0, 0);
        __syncthreads();
    }

    int bs = base[e];
#pragma unroll
    for (int i = 0; i < 2; ++i)
#pragma unroll
        for (int n = 0; n < 2; ++n) {
            int pp = wn * 32 + n * 16 + fr;
            int gca = ja * 64 + pp;  // h index in [0, 2048)
            float ba = bl1[e * H2_ + gca];
            float bb = bl1[e * H2_ + H_ + gca];
#pragma unroll
            for (int r = 0; r < 4; ++r) {
                int row = tm * 64 + wm * 32 + i * 16 + fg * 4 + r;
                if (row < cn) {
                    float a_v = acc[i][n][r] + ba;
                    float b_v = acc[i][n + 2][r] + bb;
                    float s_v = a_v / (1.f + expf(-a_v)) * b_v;
                    act[(size_t)(bs + row) * H_ + gca] = f2b(s_v);
                }
            }
        }
}

// ---------------- GEMM2: y = act@W2 + b2 ; out[token] += w*y ----------------
__global__ __launch_bounds__(256) void gemm2_kernel(
    const unsigned short* __restrict__ act, const unsigned short* __restrict__ W2T,
    const float* __restrict__ bl2, const int* __restrict__ cnt,
    const int* __restrict__ base, const int* __restrict__ perm,
    const float* __restrict__ wgt, float* __restrict__ out) {
    int e = blockIdx.z;
    int cn = cnt[e];
    int tm = blockIdx.x;
    if (tm * 64 >= cn) return;
    int jb = blockIdx.y;  // output cols [jb*128, +128)
    __shared__ __align__(16) unsigned short As[64 * 32];
    __shared__ __align__(16) unsigned short Bs[128 * 32];
    int tid = threadIdx.x, lane = tid & 63, wid = tid >> 6;
    int wm = wid >> 1, wn = wid & 1;
    v4f acc[2][4];
#pragma unroll
    for (int i = 0; i < 2; ++i)
#pragma unroll
        for (int n = 0; n < 4; ++n)
#pragma unroll
            for (int r = 0; r < 4; ++r) acc[i][n][r] = 0.f;

    int ar = tid >> 2, ag = tid & 3;
    int ap = tm * 64 + ar;
    int bs = base[e];
    const unsigned short* arow = (ap < cn) ? act + (size_t)(bs + ap) * H_ : nullptr;
    const unsigned short* w2e = W2T + (size_t)e * D_ * H_;  // (1024 x 2048) bf16

    int fr = lane & 15, fg = lane >> 4;
    int sg = (fg ^ (fr & 3)) << 3;

    for (int k0 = 0; k0 < H_; k0 += 32) {
        v8s av = {0, 0, 0, 0, 0, 0, 0, 0};
        if (arow) av = *(const v8s*)(arow + k0 + ag * 8);
        *(v8s*)(As + ar * 32 + ((ag ^ (ar & 3)) << 3)) = av;
#pragma unroll
        for (int rep = 0; rep < 2; ++rep) {
            int item = tid + rep * 256;
            int c = item >> 2, g = item & 3;
            int grow = jb * 128 + c;
            v8s bv = *(const v8s*)(w2e + (size_t)grow * H_ + k0 + g * 8);
            *(v8s*)(Bs + c * 32 + ((g ^ (c & 3)) << 3)) = bv;
        }
        __syncthreads();
        v8s a[2], b[4];
#pragma unroll
        for (int i = 0; i < 2; ++i)
            a[i] = *(const v8s*)(As + (wm * 32 + i * 16 + fr) * 32 + sg);
#pragma unroll
        for (int n = 0; n < 4; ++n)
            b[n] = *(const v8s*)(Bs + (wn * 64 + n * 16 + fr) * 32 + sg);
#pragma unroll
        for (int i = 0; i < 2; ++i)
#pragma unroll
            for (int n = 0; n < 4; ++n)
                acc[i][n] = __builtin_amdgcn_mfma_f32_16x16x32_bf16(a[i], b[n], acc[i][n], 0, 0, 0);
        __syncthreads();
    }

#pragma unroll
    for (int i = 0; i < 2; ++i)
#pragma unroll
        for (int n = 0; n < 4; ++n) {
            int col = jb * 128 + wn * 64 + n * 16 + fr;
            float b2 = bl2[e * D_ + col];
#pragma unroll
            for (int r = 0; r < 4; ++r) {
                int row = tm * 64 + wm * 32 + i * 16 + fg * 4 + r;
                if (row < cn) {
                    int tokn = perm[e * M_ + row];
                    float w = wgt[e * M_ + row];
                    atomicAdd(&out[(size_t)tokn * D_ + col], w * (acc[i][n][r] + b2));
                }
            }
        }
}

extern "C" void kernel_launch(void* const* d_in, const int* in_sizes, int n_in,
                              void* d_out, int out_size, void* d_ws, size_t ws_size,
                              hipStream_t stream) {
    const float* x = (const float*)d_in[0];
    const float* Wr = (const float*)d_in[1];
    const float* br = (const float*)d_in[2];
    const float* Wl1 = (const float*)d_in[3];
    const float* bl1 = (const float*)d_in[4];
    const float* Wl2 = (const float*)d_in[5];
    const float* bl2 = (const float*)d_in[6];
    const float* biases = (const float*)d_in[7];
    float* out = (float*)d_out;

    char* ws = (char*)d_ws;
    size_t off = 0;
    auto alloc = [&](size_t bytes) {
        char* p = ws + off;
        off += (bytes + 255) & ~(size_t)255;
        return p;
    };
    unsigned short* xb = (unsigned short*)alloc((size_t)M_ * D_ * 2);
    unsigned short* W1T = (unsigned short*)alloc((size_t)NE * H2_ * D_ * 2);
    unsigned short* W2T = (unsigned short*)alloc((size_t)NE * D_ * H_ * 2);
    unsigned short* act = (unsigned short*)alloc((size_t)M_ * 2 * H_ * 2);
    int* perm = (int*)alloc((size_t)NE * M_ * 4);
    float* wgt = (float*)alloc((size_t)NE * M_ * 4);
    int* cnt = (int*)alloc(256);
    int* base = (int*)alloc(256);
    if (ws_size < off) return;  // scratch too small: leave output untouched (diagnosable)

    hipMemsetAsync(cnt, 0, 256, stream);
    hipMemsetAsync(d_out, 0, (size_t)out_size * 4, stream);

    cvt_x_kernel<<<2048, 256, 0, stream>>>(x, xb);
    transpose_kernel<D_, H2_><<<dim3(H2_ / 32, D_ / 32, NE), 256, 0, stream>>>(Wl1, W1T);
    transpose_kernel<H_, D_><<<dim3(D_ / 32, H_ / 32, NE), 256, 0, stream>>>(Wl2, W2T);
    router_kernel<<<M_ / 4, 256, 0, stream>>>(x, Wr, br, biases, cnt, perm, wgt);
    base_kernel<<<1, 64, 0, stream>>>(cnt, base);
    gemm1_kernel<<<dim3(M_ / 64, H_ / 64, NE), 256, 0, stream>>>(xb, W1T, bl1, cnt, base, perm, act);
    gemm2_kernel<<<dim3(M_ / 64, D_ / 128, NE), 256, 0, stream>>>(act, W2T, bl2, cnt, base, perm, wgt, out);
}

// Round 2
// 721.039 us; speedup vs baseline: 1.0868x; 1.0868x over previous
//
#include <hip/hip_runtime.h>
#include <hip/hip_bf16.h>

#define D_ 1024
#define H_ 2048
#define H2_ 4096
#define NE 8
#define M_ 8192
#define BM 128
#define BN 128
#define BK 64

typedef short v8s __attribute__((ext_vector_type(8)));
typedef float v4f __attribute__((ext_vector_type(4)));

typedef const __attribute__((address_space(1))) void gvoid_t;
typedef __attribute__((address_space(3))) void svoid_t;

__device__ __forceinline__ unsigned short f2b(float f) {
    __hip_bfloat16 h = __float2bfloat16(f);
    unsigned short u;
    __builtin_memcpy(&u, &h, sizeof(u));
    return u;
}

// ---------------- prep: x -> bf16 ----------------
__global__ __launch_bounds__(256) void cvt_x_kernel(const float* __restrict__ x,
                                                    unsigned short* __restrict__ xb) {
    size_t total = (size_t)M_ * D_ / 4;
    for (size_t i = (size_t)blockIdx.x * 256 + threadIdx.x; i < total;
         i += (size_t)gridDim.x * 256) {
        float4 v = ((const float4*)x)[i];
        ushort4 o;
        o.x = f2b(v.x); o.y = f2b(v.y); o.z = f2b(v.z); o.w = f2b(v.w);
        ((ushort4*)xb)[i] = o;
    }
}

// ---------------- prep: transpose (R x C) f32 -> (C x R) bf16, per expert ----
template <int R, int C>
__global__ __launch_bounds__(256) void transpose_kernel(const float* __restrict__ in,
                                                        unsigned short* __restrict__ out) {
    __shared__ float tile[32][33];
    int e = blockIdx.z;
    const float* src = in + (size_t)e * R * C;
    unsigned short* dst = out + (size_t)e * R * C;
    int c0 = blockIdx.x * 32;
    int r0 = blockIdx.y * 32;
    int tx = threadIdx.x & 31, ty = threadIdx.x >> 5;
#pragma unroll
    for (int i = 0; i < 4; ++i)
        tile[ty + i * 8][tx] = src[(size_t)(r0 + ty + i * 8) * C + c0 + tx];
    __syncthreads();
#pragma unroll
    for (int i = 0; i < 4; ++i)
        dst[(size_t)(c0 + ty + i * 8) * R + r0 + tx] = f2b(tile[tx][ty + i * 8]);
}

// ---------------- router: scores, top2, compacted expert lists + token slots ----
__global__ __launch_bounds__(256) void router_kernel(
    const float* __restrict__ x, const float* __restrict__ Wr,
    const float* __restrict__ br, const float* __restrict__ biases,
    int* __restrict__ cnt, int* __restrict__ perm,
    int* __restrict__ slot_idx, float* __restrict__ slot_w) {
    int wid = threadIdx.x >> 6;
    int lane = threadIdx.x & 63;
    int m = blockIdx.x * 4 + wid;
    if (m >= M_) return;
    const float4* xr = (const float4*)(x + (size_t)m * D_);
    float4 xv[4];
#pragma unroll
    for (int p = 0; p < 4; ++p) xv[p] = xr[p * 64 + lane];
    float s[NE];
#pragma unroll
    for (int n = 0; n < NE; ++n) {
        const float4* wr = (const float4*)(Wr + (size_t)n * D_);
        float acc = 0.f;
#pragma unroll
        for (int p = 0; p < 4; ++p) {
            float4 w4 = wr[p * 64 + lane];
            acc += xv[p].x * w4.x + xv[p].y * w4.y + xv[p].z * w4.z + xv[p].w * w4.w;
        }
#pragma unroll
        for (int off = 32; off; off >>= 1) acc += __shfl_xor(acc, off, 64);
        s[n] = acc + br[n];
    }
    if (lane == 0) {
        float t[NE];
#pragma unroll
        for (int n = 0; n < NE; ++n) t[n] = s[n] + biases[n];
        int i0 = 0;
#pragma unroll
        for (int n = 1; n < NE; ++n) if (t[n] > t[i0]) i0 = n;
        int i1 = -1;
#pragma unroll
        for (int n = 0; n < NE; ++n) {
            if (n == i0) continue;
            if (i1 < 0 || t[n] > t[i1]) i1 = n;
        }
        // pair softmax == full softmax renormalized over the pair (exact identity)
        float mx = fmaxf(s[i0], s[i1]);
        float e0 = expf(s[i0] - mx), e1 = expf(s[i1] - mx);
        float inv = 1.f / (e0 + e1);
        int p0 = atomicAdd(&cnt[i0], 1);
        perm[i0 * M_ + p0] = m;
        slot_idx[m * 2] = (i0 << 13) | p0;
        slot_w[m * 2] = e0 * inv;
        int p1 = atomicAdd(&cnt[i1], 1);
        perm[i1 * M_ + p1] = m;
        slot_idx[m * 2 + 1] = (i1 << 13) | p1;
        slot_w[m * 2 + 1] = e1 * inv;
    }
}

__global__ void base_kernel(const int* __restrict__ cnt, int* __restrict__ base) {
    if (threadIdx.x == 0) {
        int b = 0;
        for (int n = 0; n < NE; ++n) { base[n] = b; b += cnt[n]; }
    }
}

// ---------------- GEMM1: act = silu(Xg@W1a + b1a) * (Xg@W1b + b1b) ----------------
// m97 structure: 128x128 tile (cols = 64 h-pairs: 64 a-cols + 64 b-cols paired
// lane-local within each wave), BK=64, global_load_lds(16B) staging into
// XOR-swizzled LDS (kg ^ row&7, applied on SOURCE addr and READ addr; dest linear).
__global__ __launch_bounds__(256) void gemm1_kernel(
    const unsigned short* __restrict__ xb, const unsigned short* __restrict__ W1T,
    const float* __restrict__ bl1, const int* __restrict__ cnt,
    const int* __restrict__ base, const int* __restrict__ perm,
    unsigned short* __restrict__ act) {
    int e = blockIdx.z;
    int cn = cnt[e];
    int tm = blockIdx.x;
    if (tm * BM >= cn) return;
    int jb = blockIdx.y;  // h-pair block [jb*64, +64)
    __shared__ __align__(16) unsigned short As[BM * BK];
    __shared__ __align__(16) unsigned short Bs[BN * BK];
    int tid = threadIdx.x, lane = tid & 63, wid = tid >> 6;
    int wm = wid >> 1, wn = wid & 1;
    int fr = lane & 15, fg = lane >> 4;

    // staging geometry: slot s = j*256+tid; row = s>>3 (16B groups of 8 per row)
    int srow0 = tid >> 3;   // + j*32
    int kgs = tid & 7;      // LDS 16B-slot within row
    const unsigned short* aptr[4];
    const unsigned short* bptr[4];
    const unsigned short* w1e = W1T + (size_t)e * H2_ * D_;
#pragma unroll
    for (int j = 0; j < 4; ++j) {
        int row = j * 32 + srow0;
        int ap = tm * BM + row;
        int tok = perm[e * M_ + min(ap, cn - 1)];
        aptr[j] = xb + (size_t)tok * D_ + ((kgs ^ (row & 7)) << 3);
        int c = row;  // B staging col index
        int cc = c & 63, wnc = c >> 6;
        int half = cc >> 5;
        int p = wnc * 32 + (cc & 31);
        int grow = half * H_ + jb * 64 + p;
        bptr[j] = w1e + (size_t)grow * D_ + ((kgs ^ (c & 7)) << 3);
    }

    v4f acc[4][4] = {};
    unsigned short* asl = As + tid * 8;  // 16 B per thread, linear dest
    unsigned short* bsl = Bs + tid * 8;

    for (int k0 = 0; k0 < D_; k0 += BK) {
#pragma unroll
        for (int j = 0; j < 4; ++j)
            __builtin_amdgcn_global_load_lds((gvoid_t*)(aptr[j]), (svoid_t*)(asl + j * 2048), 16, 0, 0);
#pragma unroll
        for (int j = 0; j < 4; ++j)
            __builtin_amdgcn_global_load_lds((gvoid_t*)(bptr[j]), (svoid_t*)(bsl + j * 2048), 16, 0, 0);
#pragma unroll
        for (int j = 0; j < 4; ++j) { aptr[j] += BK; bptr[j] += BK; }
        __syncthreads();
#pragma unroll
        for (int kk = 0; kk < 2; ++kk) {
            v8s a[4], b[4];
#pragma unroll
            for (int i = 0; i < 4; ++i) {
                int row = wm * 64 + i * 16 + fr;
                a[i] = *(const v8s*)(As + row * BK + (((kk * 4 + fg) ^ (row & 7)) << 3));
            }
#pragma unroll
            for (int n = 0; n < 4; ++n) {
                int col = wn * 64 + n * 16 + fr;
                b[n] = *(const v8s*)(Bs + col * BK + (((kk * 4 + fg) ^ (col & 7)) << 3));
            }
#pragma unroll
            for (int i = 0; i < 4; ++i)
#pragma unroll
                for (int n = 0; n < 4; ++n)
                    acc[i][n] = __builtin_amdgcn_mfma_f32_16x16x32_bf16(a[i], b[n], acc[i][n], 0, 0, 0);
        }
        __syncthreads();
    }

    int bs = base[e];
#pragma unroll
    for (int i = 0; i < 4; ++i)
#pragma unroll
        for (int n = 0; n < 2; ++n) {
            int gca = jb * 64 + wn * 32 + n * 16 + fr;  // h in [0, 2048)
            float ba = bl1[e * H2_ + gca];
            float bb = bl1[e * H2_ + H_ + gca];
#pragma unroll
            for (int r = 0; r < 4; ++r) {
                int row = tm * BM + wm * 64 + i * 16 + fg * 4 + r;
                if (row < cn) {
                    float a_v = acc[i][n][r] + ba;
                    float b_v = acc[i][n + 2][r] + bb;
                    float s_v = a_v / (1.f + __expf(-a_v)) * b_v;
                    act[(size_t)(bs + row) * H_ + gca] = f2b(s_v);
                }
            }
        }
}

// ---------------- GEMM2: y[slot] = act@W2 + b2 (plain stores, no atomics) ----
__global__ __launch_bounds__(256) void gemm2_kernel(
    const unsigned short* __restrict__ act, const unsigned short* __restrict__ W2T,
    const float* __restrict__ bl2, const int* __restrict__ cnt,
    const int* __restrict__ base, float* __restrict__ y) {
    int e = blockIdx.z;
    int cn = cnt[e];
    int tm = blockIdx.x;
    if (tm * BM >= cn) return;
    int jb = blockIdx.y;  // out cols [jb*128, +128)
    __shared__ __align__(16) unsigned short As[BM * BK];
    __shared__ __align__(16) unsigned short Bs[BN * BK];
    int tid = threadIdx.x, lane = tid & 63, wid = tid >> 6;
    int wm = wid >> 1, wn = wid & 1;
    int fr = lane & 15, fg = lane >> 4;
    int bs = base[e];

    int srow0 = tid >> 3;
    int kgs = tid & 7;
    const unsigned short* aptr[4];
    const unsigned short* bptr[4];
    const unsigned short* w2e = W2T + (size_t)e * D_ * H_;
#pragma unroll
    for (int j = 0; j < 4; ++j) {
        int row = j * 32 + srow0;
        int ap = min(tm * BM + row, cn - 1);
        aptr[j] = act + (size_t)(bs + ap) * H_ + ((kgs ^ (row & 7)) << 3);
        int grow = jb * BN + row;
        bptr[j] = w2e + (size_t)grow * H_ + ((kgs ^ (row & 7)) << 3);
    }

    v4f acc[4][4] = {};
    unsigned short* asl = As + tid * 8;
    unsigned short* bsl = Bs + tid * 8;

    for (int k0 = 0; k0 < H_; k0 += BK) {
#pragma unroll
        for (int j = 0; j < 4; ++j)
            __builtin_amdgcn_global_load_lds((gvoid_t*)(aptr[j]), (svoid_t*)(asl + j * 2048), 16, 0, 0);
#pragma unroll
        for (int j = 0; j < 4; ++j)
            __builtin_amdgcn_global_load_lds((gvoid_t*)(bptr[j]), (svoid_t*)(bsl + j * 2048), 16, 0, 0);
#pragma unroll
        for (int j = 0; j < 4; ++j) { aptr[j] += BK; bptr[j] += BK; }
        __syncthreads();
#pragma unroll
        for (int kk = 0; kk < 2; ++kk) {
            v8s a[4], b[4];
#pragma unroll
            for (int i = 0; i < 4; ++i) {
                int row = wm * 64 + i * 16 + fr;
                a[i] = *(const v8s*)(As + row * BK + (((kk * 4 + fg) ^ (row & 7)) << 3));
            }
#pragma unroll
            for (int n = 0; n < 4; ++n) {
                int col = wn * 64 + n * 16 + fr;
                b[n] = *(const v8s*)(Bs + col * BK + (((kk * 4 + fg) ^ (col & 7)) << 3));
            }
#pragma unroll
            for (int i = 0; i < 4; ++i)
#pragma unroll
                for (int n = 0; n < 4; ++n)
                    acc[i][n] = __builtin_amdgcn_mfma_f32_16x16x32_bf16(a[i], b[n], acc[i][n], 0, 0, 0);
        }
        __syncthreads();
    }

#pragma unroll
    for (int i = 0; i < 4; ++i)
#pragma unroll
        for (int n = 0; n < 4; ++n) {
            int col = jb * BN + wn * 64 + n * 16 + fr;
            float b2 = bl2[e * D_ + col];
#pragma unroll
            for (int r = 0; r < 4; ++r) {
                int row = tm * BM + wm * 64 + i * 16 + fg * 4 + r;
                if (row < cn)
                    y[(size_t)(bs + row) * D_ + col] = acc[i][n][r] + b2;
            }
        }
}

// ---------------- combine: out[m] = w0*y[slot0] + w1*y[slot1] ----------------
__global__ __launch_bounds__(256) void combine_kernel(
    const float* __restrict__ y, const int* __restrict__ slot_idx,
    const float* __restrict__ slot_w, const int* __restrict__ base,
    float* __restrict__ out) {
    int m = blockIdx.x;
    int i0 = slot_idx[m * 2], i1 = slot_idx[m * 2 + 1];
    float w0 = slot_w[m * 2], w1 = slot_w[m * 2 + 1];
    const float4* y0 = (const float4*)(y + (size_t)(base[i0 >> 13] + (i0 & (M_ - 1))) * D_);
    const float4* y1 = (const float4*)(y + (size_t)(base[i1 >> 13] + (i1 & (M_ - 1))) * D_);
    float4* o = (float4*)(out + (size_t)m * D_);
    int t = threadIdx.x;  // D/4 = 256
    float4 a = y0[t], b = y1[t];
    float4 r;
    r.x = w0 * a.x + w1 * b.x;
    r.y = w0 * a.y + w1 * b.y;
    r.z = w0 * a.z + w1 * b.z;
    r.w = w0 * a.w + w1 * b.w;
    o[t] = r;
}

extern "C" void kernel_launch(void* const* d_in, const int* in_sizes, int n_in,
                              void* d_out, int out_size, void* d_ws, size_t ws_size,
                              hipStream_t stream) {
    const float* x = (const float*)d_in[0];
    const float* Wr = (const float*)d_in[1];
    const float* br = (const float*)d_in[2];
    const float* Wl1 = (const float*)d_in[3];
    const float* bl1 = (const float*)d_in[4];
    const float* Wl2 = (const float*)d_in[5];
    const float* bl2 = (const float*)d_in[6];
    const float* biases = (const float*)d_in[7];
    float* out = (float*)d_out;

    char* ws = (char*)d_ws;
    size_t off = 0;
    auto alloc = [&](size_t bytes) {
        char* p = ws + off;
        off += (bytes + 255) & ~(size_t)255;
        return p;
    };
    unsigned short* xb = (unsigned short*)alloc((size_t)M_ * D_ * 2);
    unsigned short* W1T = (unsigned short*)alloc((size_t)NE * H2_ * D_ * 2);
    unsigned short* W2T = (unsigned short*)alloc((size_t)NE * D_ * H_ * 2);
    unsigned short* act = (unsigned short*)alloc((size_t)M_ * 2 * H_ * 2);
    int* perm = (int*)alloc((size_t)NE * M_ * 4);
    int* slot_idx = (int*)alloc((size_t)M_ * 2 * 4);
    float* slot_w = (float*)alloc((size_t)M_ * 2 * 4);
    int* cnt = (int*)alloc(256);
    int* base = (int*)alloc(256);
    // y (16384 x 1024 f32 = 64 MB) aliases W1T (64 MB): W1T is dead after gemm1.
    float* y = (float*)W1T;
    if (ws_size < off) return;  // scratch too small: leave output untouched (diagnosable)

    hipMemsetAsync(cnt, 0, 256, stream);

    cvt_x_kernel<<<2048, 256, 0, stream>>>(x, xb);
    transpose_kernel<D_, H2_><<<dim3(H2_ / 32, D_ / 32, NE), 256, 0, stream>>>(Wl1, W1T);
    transpose_kernel<H_, D_><<<dim3(D_ / 32, H_ / 32, NE), 256, 0, stream>>>(Wl2, W2T);
    router_kernel<<<M_ / 4, 256, 0, stream>>>(x, Wr, br, biases, cnt, perm, slot_idx, slot_w);
    base_kernel<<<1, 64, 0, stream>>>(cnt, base);
    gemm1_kernel<<<dim3(M_ / BM, H_ / 64, NE), 256, 0, stream>>>(xb, W1T, bl1, cnt, base, perm, act);
    gemm2_kernel<<<dim3(M_ / BM, D_ / BN, NE), 256, 0, stream>>>(act, W2T, bl2, cnt, base, y);
    combine_kernel<<<M_, 256, 0, stream>>>(y, slot_idx, slot_w, base, out);
}